// Round 6
// baseline (121.052 us; speedup 1.0000x reference)
//
#include <hip/hip_runtime.h>
#include <hip/hip_bf16.h>
#include <math.h>

#define NB 4096     // batch
#define NN 8192     // N = B * n_views
#define DD 128      // feature dim
#define NSPLIT 16   // j-splits; 512 cols per block
#define CHUNK 64    // cols per LDS-staged chunk
#define NCHUNK 8    // 512 / 64

constexpr float INV_T = 14.285714285714286f;   // 1/0.07 (= subtracted row max M)
constexpr float EC1   = 20.609929155556620f;   // INV_T * log2(e)
constexpr float EC0   = -20.609929155556620f;  // -INV_T * log2(e)
constexpr float LN2   = 0.6931471805599453f;

typedef __attribute__((ext_vector_type(8))) short bf16x8;
typedef __attribute__((ext_vector_type(4))) float f32x4;

__device__ __forceinline__ float bf2f(ushort u) {
    union { unsigned int i; float f; } v; v.i = ((unsigned int)u) << 16; return v.f;
}

// ---- kernel 1: L2-normalize rows -> bf16 + selfdot; zero accumulators ----
__global__ __launch_bounds__(256) void k_norm(const float* __restrict__ feat,
                                              ushort* __restrict__ fb,
                                              float* __restrict__ selfdot,
                                              float* __restrict__ zbase,  // g_se..g_ct..cnt: 3*NN+32 dwords
                                              float* __restrict__ out) {
    const int gid = blockIdx.x * 256 + threadIdx.x;
    if (gid < 3 * NN + 32) zbase[gid] = 0.0f;   // zero g_se/g_ps/g_ct + cnt (bit-zero == int 0)
    if (gid == 0) out[0] = 0.0f;

    const int r    = gid >> 6;                  // one wave per row
    const int lane = threadIdx.x & 63;
    const float2 v = ((const float2*)(feat + (size_t)r * DD))[lane];
    float ss = v.x * v.x + v.y * v.y;
#pragma unroll
    for (int off = 1; off < 64; off <<= 1) ss += __shfl_xor(ss, off, 64);
    const float scale = 1.0f / fmaxf(sqrtf(ss), 1e-12f);
    __hip_bfloat162 h2;
    h2.x = __float2bfloat16(v.x * scale);
    h2.y = __float2bfloat16(v.y * scale);
    ((__hip_bfloat162*)(fb + (size_t)r * DD))[lane] = h2;
    // self-dot of the QUANTIZED row (matches the MFMA diagonal)
    const float xb = bf2f(((ushort2*)&h2)->x), yb = bf2f(((ushort2*)&h2)->y);
    float s2 = xb * xb + yb * yb;
#pragma unroll
    for (int off = 1; off < 64; off <<= 1) s2 += __shfl_xor(s2, off, 64);
    if (lane == 0) selfdot[r] = s2;
}

// stage one 64-col chunk's B-fragments into LDS, fragment-major.
// Wave w stages j-tile jt=w. LDS dst = wave-uniform base + lane*16 (HW rule);
// per-lane GLOBAL address does the fragment gather.
__device__ __forceinline__ void stage_chunk(const ushort* __restrict__ fb, ushort* sbuf,
                                            int jb, int w, int n15, int q) {
    const ushort* g = fb + (size_t)(jb + w * 16 + n15) * DD + q * 8;
#pragma unroll
    for (int kt = 0; kt < 4; ++kt)
        __builtin_amdgcn_global_load_lds(
            (const __attribute__((address_space(1))) void*)(g + kt * 32),
            (__attribute__((address_space(3))) void*)(sbuf + (w * 4 + kt) * 512),
            16, 0, 0);
}

// ---- kernel 2: F*F^T, LDS double-buffered B, fused epilogue + finalize ----
// Block: 256 rows x 512 cols, 4 waves (64 rows each). Grid 512 = 32 rb x 16 js.
// Last-finishing block per rb runs the per-row finalize for its 256 rows.
__global__ __launch_bounds__(256, 2) void k_main(const ushort* __restrict__ fb,
                                                 const int* __restrict__ labels,
                                                 const float* __restrict__ selfdot,
                                                 float* __restrict__ g_se,
                                                 float* __restrict__ g_ps,
                                                 float* __restrict__ g_ct,
                                                 int* __restrict__ cnt,
                                                 float* __restrict__ out) {
    __shared__ ushort sB[2][CHUNK * DD];   // 2 x 16 KB, fragment-major
    __shared__ int slab[512];
    __shared__ int lastflag;
    __shared__ float sred[4];

    const int tid  = threadIdx.x;
    const int lane = tid & 63;
    const int w    = tid >> 6;
    const int rb   = blockIdx.x >> 4;           // 0..31
    const int js   = blockIdx.x & (NSPLIT - 1); // 0..15
    const int i0   = rb * 256 + w * 64;
    const int jb0  = js * 512;
    const int q    = lane >> 4;
    const int n15  = lane & 15;

    slab[tid]       = labels[(jb0 + tid) & (NB - 1)];
    slab[tid + 256] = labels[(jb0 + tid + 256) & (NB - 1)];

    // A fragments: 4 row-tiles x 4 kt (64 regs), resident whole kernel
    bf16x8 afrag[4][4];
#pragma unroll
    for (int tt = 0; tt < 4; ++tt) {
        const ushort* rp = fb + (size_t)(i0 + tt * 16 + n15) * DD + q * 8;
#pragma unroll
        for (int kt = 0; kt < 4; ++kt) afrag[tt][kt] = *(const bf16x8*)(rp + kt * 32);
    }
    int labi[16];
#pragma unroll
    for (int tt = 0; tt < 4; ++tt)
#pragma unroll
        for (int r = 0; r < 4; ++r)
            labi[tt * 4 + r] = labels[(i0 + tt * 16 + q * 4 + r) & (NB - 1)];

    float a_se[16] = {}, a_ps[16] = {}, a_ct[16] = {};

    stage_chunk(fb, &sB[0][0], jb0, w, n15, q);
    __syncthreads();

    for (int c = 0; c < NCHUNK; ++c) {
        if (c + 1 < NCHUNK)
            stage_chunk(fb, &sB[(c + 1) & 1][0], jb0 + (c + 1) * CHUNK, w, n15, q);
        const ushort* sb = &sB[c & 1][0];
        const int crel = c * CHUNK;
#pragma unroll
        for (int jt = 0; jt < 4; ++jt) {
            bf16x8 bf[4];
#pragma unroll
            for (int kt = 0; kt < 4; ++kt)
                bf[kt] = *(const bf16x8*)(sb + (jt * 4 + kt) * 512 + lane * 8); // conflict-free
            const int labj = slab[crel + jt * 16 + n15];
            f32x4 acc[4];
#pragma unroll
            for (int tt = 0; tt < 4; ++tt) acc[tt] = (f32x4){0.f, 0.f, 0.f, 0.f};
#pragma unroll
            for (int kt = 0; kt < 4; ++kt)
#pragma unroll
                for (int tt = 0; tt < 4; ++tt)
                    acc[tt] = __builtin_amdgcn_mfma_f32_16x16x32_bf16(afrag[tt][kt], bf[kt], acc[tt], 0, 0, 0);
#pragma unroll
            for (int tt = 0; tt < 4; ++tt)
#pragma unroll
                for (int r = 0; r < 4; ++r) {
                    const float d = acc[tt][r];
                    a_se[tt * 4 + r] += __builtin_amdgcn_exp2f(fmaf(d, EC1, EC0));
                    const bool m = (labi[tt * 4 + r] == labj);
                    a_ps[tt * 4 + r] += m ? d : 0.0f;     // raw dot; scaled in finalize
                    a_ct[tt * 4 + r] += m ? 1.0f : 0.0f;
                }
        }
        __syncthreads();
    }

    // quad-reduce (16 lanes share rows) then one atomicAdd per row per value
#pragma unroll
    for (int s = 0; s < 16; ++s) {
        float v1 = a_se[s], v2 = a_ps[s], v3 = a_ct[s];
#pragma unroll
        for (int off = 1; off < 16; off <<= 1) {
            v1 += __shfl_xor(v1, off, 64);
            v2 += __shfl_xor(v2, off, 64);
            v3 += __shfl_xor(v3, off, 64);
        }
        if (n15 == 0) {
            const int row = i0 + (s >> 2) * 16 + q * 4 + (s & 3);
            atomicAdd(&g_se[row], v1);
            atomicAdd(&g_ps[row], v2);
            atomicAdd(&g_ct[row], v3);
        }
    }

    // ---- last-block-per-rb finalize (no spin; cannot deadlock) ----
    __syncthreads();
    __threadfence();
    if (tid == 0) lastflag = (atomicAdd(&cnt[rb], 1) == NSPLIT - 1);
    __syncthreads();
    if (lastflag) {
        __threadfence();
        const int r = rb * 256 + tid;
        const float se0 = g_se[r], ps = g_ps[r], ct0 = g_ct[r];
        const float sd  = selfdot[r];
        const float se  = se0 - __builtin_amdgcn_exp2f(fmaf(sd, EC1, EC0));
        const float ct  = ct0 - 1.0f;
        const float possum = INV_T * (ps - sd - ct);
        const float lg  = __builtin_amdgcn_logf(se + 1e-12f) * LN2;
        const float mlpp = (possum - ct * lg) / fmaxf(ct, 1.0f);
        float v = -mlpp * (1.0f / (float)NN);
#pragma unroll
        for (int off = 1; off < 64; off <<= 1) v += __shfl_xor(v, off, 64);
        if (lane == 0) sred[w] = v;
        __syncthreads();
        if (tid == 0) atomicAdd(out, sred[0] + sred[1] + sred[2] + sred[3]);
    }
}

extern "C" void kernel_launch(void* const* d_in, const int* in_sizes, int n_in,
                              void* d_out, int out_size, void* d_ws, size_t ws_size,
                              hipStream_t stream) {
    const float* feat = (const float*)d_in[0];
    const int* labels = (const int*)d_in[1];
    float* out        = (float*)d_out;
    char* ws          = (char*)d_ws;

    ushort* fb      = (ushort*)ws;                                   // 2 MB
    float* selfdot  = (float*)(ws + (size_t)2 * 1024 * 1024);        // NN f32
    float* g_se     = selfdot + NN;                                  // NN f32
    float* g_ps     = g_se + NN;
    float* g_ct     = g_ps + NN;
    int*   cnt      = (int*)(g_ct + NN);                             // 32 i32

    k_norm<<<NN / 4, 256, 0, stream>>>(feat, fb, selfdot, g_se, out);
    k_main<<<32 * NSPLIT, 256, 0, stream>>>(fb, labels, selfdot, g_se, g_ps, g_ct, cnt, out);
}